// Round 4
// baseline (274.250 us; speedup 1.0000x reference)
//
#include <hip/hip_runtime.h>

#define FEAT 128
#define HID  128
#define XS_S 132  // 128 nodes + 4 pad; multiple of 4 keeps b128 alignment

// ---------------------------------------------------------------------------
// Kernel 1: [A|B] = X @ [W1[:128] | W1[128:]]  (N x 256 concat, fp32)
// Block: 256 threads -> 128 nodes x 64 concat-cols. Micro-tile 4 nodes x 8
// cols. K chunked by 32; xs = X^T chunk in LDS (16.9 KB -> 9 blocks/CU by
// LDS). W is NOT staged in LDS: per-wave w reads are same-address broadcasts,
// served from L1/L2 via one coalesced request — removing them from LDS takes
// the per-wave-k LDS cost from 3 b128 (36 cyc, CU-serial) to 1 (12 cyc),
// flipping the kernel from LDS-instruction-bound (44% VALU) to VALU-bound.
// ---------------------------------------------------------------------------
__global__ __launch_bounds__(256) void gemm_ab(
    const float* __restrict__ X, const float* __restrict__ W1,
    float* __restrict__ A, float* __restrict__ B, int N) {
  __shared__ float xs[32 * XS_S];
  const int t = threadIdx.x;
  const int n0 = blockIdx.x * 128;
  const int j0 = blockIdx.y * 64;  // concat col base: 0,64 -> A ; 128,192 -> B
  const float* Wbase = W1 + (j0 < 128 ? j0 : 128 * HID + (j0 - 128));
  float* Obase = (j0 < 128) ? (A + j0) : (B + (j0 - 128));

  const int tn = t & 31;  // node group: nodes tn*4 .. tn*4+3
  const int tc = t >> 5;  // col group:  cols  tc*8 .. tc*8+7

  float acc[4][8];
#pragma unroll
  for (int r = 0; r < 4; ++r)
#pragma unroll
    for (int c = 0; c < 8; ++c) acc[r][c] = 0.f;

  const int ln = t >> 3;       // staging node 0..31 (+rep*32)
  const int lf = (t & 7) * 4;  // staging k-local float4 base

  for (int kc = 0; kc < 4; ++kc) {
    __syncthreads();
    // stage X chunk transposed: xs[k_local][node]
#pragma unroll
    for (int rep = 0; rep < 4; ++rep) {
      const int nl = ln + rep * 32;
      const int n = n0 + nl;
      float4 v = make_float4(0.f, 0.f, 0.f, 0.f);
      if (n < N) v = *(const float4*)(X + (size_t)n * FEAT + kc * 32 + lf);
      xs[(lf + 0) * XS_S + nl] = v.x;
      xs[(lf + 1) * XS_S + nl] = v.y;
      xs[(lf + 2) * XS_S + nl] = v.z;
      xs[(lf + 3) * XS_S + nl] = v.w;
    }
    __syncthreads();

#pragma unroll 8
    for (int k = 0; k < 32; ++k) {
      const float* wk = Wbase + (size_t)(kc * 32 + k) * HID + tc * 8;
      const float4 w0 = *(const float4*)wk;        // wave-broadcast, L1/L2
      const float4 w1 = *(const float4*)(wk + 4);
      const float4 xv = *(const float4*)&xs[k * XS_S + tn * 4];
      const float xr[4] = {xv.x, xv.y, xv.z, xv.w};
#pragma unroll
      for (int r = 0; r < 4; ++r) {
        acc[r][0] = fmaf(xr[r], w0.x, acc[r][0]);
        acc[r][1] = fmaf(xr[r], w0.y, acc[r][1]);
        acc[r][2] = fmaf(xr[r], w0.z, acc[r][2]);
        acc[r][3] = fmaf(xr[r], w0.w, acc[r][3]);
        acc[r][4] = fmaf(xr[r], w1.x, acc[r][4]);
        acc[r][5] = fmaf(xr[r], w1.y, acc[r][5]);
        acc[r][6] = fmaf(xr[r], w1.z, acc[r][6]);
        acc[r][7] = fmaf(xr[r], w1.w, acc[r][7]);
      }
    }
  }

#pragma unroll
  for (int r = 0; r < 4; ++r) {
    const int n = n0 + tn * 4 + r;
    if (n < N) {
      float* o = Obase + (size_t)n * HID + tc * 8;
      *(float4*)o = make_float4(acc[r][0], acc[r][1], acc[r][2], acc[r][3]);
      *(float4*)(o + 4) = make_float4(acc[r][4], acc[r][5], acc[r][6], acc[r][7]);
    }
  }
}

// ---------------------------------------------------------------------------
// Kernel 2: CSR row offsets from sorted src via binary search. rs has N+1 ents.
// ---------------------------------------------------------------------------
__global__ __launch_bounds__(256) void row_offsets(
    const int* __restrict__ src, int* __restrict__ rs, int N, int E) {
  const int n = blockIdx.x * 256 + threadIdx.x;
  if (n > N) return;
  int lo = 0, hi = E;
  while (lo < hi) {
    const int mid = (lo + hi) >> 1;
    if (src[mid] < n) lo = mid + 1; else hi = mid;
  }
  rs[n] = lo;
}

// ---------------------------------------------------------------------------
// Kernel 3: z[e] = W2 . relu(A[src[e]] + B[dst[e]] + b1) + b2
// 16 lanes/edge, 2 edges per group, 4 batches per block with a 2-stage
// software pipeline: batch i+1's 8 row loads are issued BEFORE batch i's
// shfl-reduce chain, so misses stay in flight across the serial reduce.
// ---------------------------------------------------------------------------
struct Rows { float4 a0, a1, b0, b1, c0, c1, d0, d1; };

__device__ __forceinline__ void load_pair(
    const float* __restrict__ A, const float* __restrict__ B,
    const int* __restrict__ src, const int* __restrict__ dst,
    int e0, int E, int l, Rows& r) {
  const bool k0 = e0 < E, k1 = e0 + 1 < E;
  const int u0 = k0 ? src[e0] : 0;
  const int v0 = k0 ? dst[e0] : 0;
  const int u1 = k1 ? src[e0 + 1] : 0;
  const int v1 = k1 ? dst[e0 + 1] : 0;
  const float4* Au0 = (const float4*)(A + (size_t)u0 * HID) + l * 2;
  const float4* Bv0 = (const float4*)(B + (size_t)v0 * HID) + l * 2;
  const float4* Au1 = (const float4*)(A + (size_t)u1 * HID) + l * 2;
  const float4* Bv1 = (const float4*)(B + (size_t)v1 * HID) + l * 2;
  r.a0 = Au0[0]; r.a1 = Au0[1];
  r.b0 = Bv0[0]; r.b1 = Bv0[1];
  r.c0 = Au1[0]; r.c1 = Au1[1];
  r.d0 = Bv1[0]; r.d1 = Bv1[1];
}

__global__ __launch_bounds__(256) void edge_z(
    const float* __restrict__ A, const float* __restrict__ B,
    const float* __restrict__ b1, const float* __restrict__ W2,
    const float* __restrict__ b2, const int* __restrict__ src,
    const int* __restrict__ dst, float* __restrict__ z, int E) {
  const int g = threadIdx.x >> 4;
  const int l = threadIdx.x & 15;
  const int base = blockIdx.x * 128 + g * 2;

  const float4 c0 = *(const float4*)(b1 + l * 8);
  const float4 c1 = *(const float4*)(b1 + l * 8 + 4);
  const float4 w0 = *(const float4*)(W2 + l * 8);
  const float4 w1 = *(const float4*)(W2 + l * 8 + 4);
  const float bias2 = b2[0];

  Rows cur, nxt;
  load_pair(A, B, src, dst, base, E, l, cur);

#pragma unroll 4
  for (int it = 0; it < 4; ++it) {
    const int e0 = base + it * 32;
    if (it < 3) load_pair(A, B, src, dst, base + (it + 1) * 32, E, l, nxt);

    float p0 = fmaxf(cur.a0.x + cur.b0.x + c0.x, 0.f) * w0.x
             + fmaxf(cur.a0.y + cur.b0.y + c0.y, 0.f) * w0.y
             + fmaxf(cur.a0.z + cur.b0.z + c0.z, 0.f) * w0.z
             + fmaxf(cur.a0.w + cur.b0.w + c0.w, 0.f) * w0.w
             + fmaxf(cur.a1.x + cur.b1.x + c1.x, 0.f) * w1.x
             + fmaxf(cur.a1.y + cur.b1.y + c1.y, 0.f) * w1.y
             + fmaxf(cur.a1.z + cur.b1.z + c1.z, 0.f) * w1.z
             + fmaxf(cur.a1.w + cur.b1.w + c1.w, 0.f) * w1.w;
    float p1 = fmaxf(cur.c0.x + cur.d0.x + c0.x, 0.f) * w0.x
             + fmaxf(cur.c0.y + cur.d0.y + c0.y, 0.f) * w0.y
             + fmaxf(cur.c0.z + cur.d0.z + c0.z, 0.f) * w0.z
             + fmaxf(cur.c0.w + cur.d0.w + c0.w, 0.f) * w0.w
             + fmaxf(cur.c1.x + cur.d1.x + c1.x, 0.f) * w1.x
             + fmaxf(cur.c1.y + cur.d1.y + c1.y, 0.f) * w1.y
             + fmaxf(cur.c1.z + cur.d1.z + c1.z, 0.f) * w1.z
             + fmaxf(cur.c1.w + cur.d1.w + c1.w, 0.f) * w1.w;

#pragma unroll
    for (int m = 8; m >= 1; m >>= 1) {
      p0 += __shfl_xor(p0, m);
      p1 += __shfl_xor(p1, m);
    }
    if (l == 0 && e0 < E) {
      z[e0] = p0 + bias2;
      if (e0 + 1 < E) z[e0 + 1] = p1 + bias2;
    }
    cur = nxt;
  }
}

// ---------------------------------------------------------------------------
// Kernel 4: per-node log-softmax + K Gumbel rounds. TWO nodes per wave
// (half-wave each; deg<=32 fast path). ex = exp(s) space: argmax(ex) ==
// argmax(s); fused max+argmax pair reduction; fast __logf/__expf.
// ---------------------------------------------------------------------------
__global__ __launch_bounds__(256) void seg_sample(
    const float* __restrict__ z, const float* __restrict__ U,
    const int* __restrict__ dst, const int* __restrict__ rs,
    float* __restrict__ out_sel, float* __restrict__ out_soft,
    int N, int E, int K) {
  const int t = threadIdx.x;
  const int lane = t & 63;
  const int half = lane >> 5;
  const int hl = lane & 31;
  const int n = blockIdx.x * 8 + (t >> 6) * 2 + half;
  const float INVTAU = 1.0f / 0.9991f;

  int start = 0, deg = 0;
  if (n < N) { start = rs[n]; deg = rs[n + 1] - start; }

  if (__all(deg <= 32)) {
    // ---- fast path: half-wave per node ----
    if (n >= N) return;
    if (deg == 0) {
      if (hl == 0)
        for (int k = 0; k < K; ++k) out_sel[(size_t)k * N + n] = -2147483648.0f;
      return;
    }
    const bool act = hl < deg;
    const int e = start + (act ? hl : 0);
    const float zv = act ? z[e] : -INFINITY;
    const int d = act ? dst[e] : -1;

    float zmax = zv;
#pragma unroll
    for (int m = 16; m >= 1; m >>= 1) zmax = fmaxf(zmax, __shfl_xor(zmax, m));
    float den = act ? __expf(zv - zmax) : 0.f;
#pragma unroll
    for (int m = 16; m >= 1; m >>= 1) den += __shfl_xor(den, m);
    const float lpb = (zv - zmax) - __logf(den);  // per-edge log-prob

    for (int k = 0; k < K; ++k) {
      float ex = 0.f;
      if (act) {
        const float uu = U[(size_t)k * E + e];
        const float t2 = -__logf(uu);
        const float g = -__logf(t2);
        ex = __expf((lpb + g) * INVTAU);  // exp(s); s in [-19, 15] -> safe
      }
      float d2 = ex;
      float mx = ex;
      int md = d;
#pragma unroll
      for (int m = 16; m >= 1; m >>= 1) {
        d2 += __shfl_xor(d2, m);
        const float ox = __shfl_xor(mx, m);
        const int od = __shfl_xor(md, m);
        if (ox > mx) { mx = ox; md = od; }
        else if (ox == mx) md = max(md, od);
      }
      if (hl == 0) out_sel[(size_t)k * N + n] = (float)md;
      if (act) {
        const float inv = __builtin_amdgcn_rcpf(d2);
        out_soft[(size_t)k * E + e] = ex * inv;
      }
    }
    return;
  }

  // ---- general path (some deg > 32, rare): full wave per node, x2 ----
  const int wbase = blockIdx.x * 8 + (t >> 6) * 2;
  for (int j = 0; j < 2; ++j) {
    const int nn = wbase + j;
    if (nn >= N) continue;
    const int st = rs[nn];
    const int dg = rs[nn + 1] - st;
    if (dg == 0) {
      if (lane == 0)
        for (int k = 0; k < K; ++k) out_sel[(size_t)k * N + nn] = -2147483648.0f;
      continue;
    }
    float zmax = -INFINITY;
    for (int c = lane; c < dg; c += 64) zmax = fmaxf(zmax, z[st + c]);
#pragma unroll
    for (int m = 32; m >= 1; m >>= 1) zmax = fmaxf(zmax, __shfl_xor(zmax, m));
    float den = 0.f;
    for (int c = lane; c < dg; c += 64) den += expf(z[st + c] - zmax);
#pragma unroll
    for (int m = 32; m >= 1; m >>= 1) den += __shfl_xor(den, m);
    const float logd = logf(den);

    for (int k = 0; k < K; ++k) {
      float m2 = -INFINITY;
      for (int c = lane; c < dg; c += 64) {
        const int e = st + c;
        const float g = -logf(-logf(U[(size_t)k * E + e]));
        const float s = ((z[e] - zmax) - logd + g) * INVTAU;
        m2 = fmaxf(m2, s);
      }
#pragma unroll
      for (int m = 32; m >= 1; m >>= 1) m2 = fmaxf(m2, __shfl_xor(m2, m));
      float d2 = 0.f;
      int cand = -1;
      for (int c = lane; c < dg; c += 64) {
        const int e = st + c;
        const float g = -logf(-logf(U[(size_t)k * E + e]));
        const float s = ((z[e] - zmax) - logd + g) * INVTAU;
        d2 += expf(s - m2);
        if (s >= m2) cand = max(cand, dst[e]);
      }
#pragma unroll
      for (int m = 32; m >= 1; m >>= 1) d2 += __shfl_xor(d2, m);
#pragma unroll
      for (int m = 32; m >= 1; m >>= 1) cand = max(cand, __shfl_xor(cand, m));
      if (lane == 0) out_sel[(size_t)k * N + nn] = (float)cand;
      for (int c = lane; c < dg; c += 64) {
        const int e = st + c;
        const float g = -logf(-logf(U[(size_t)k * E + e]));
        const float s = ((z[e] - zmax) - logd + g) * INVTAU;
        out_soft[(size_t)k * E + e] = expf(s - m2) / d2;
      }
    }
  }
}

// ---------------------------------------------------------------------------
extern "C" void kernel_launch(void* const* d_in, const int* in_sizes, int n_in,
                              void* d_out, int out_size, void* d_ws, size_t ws_size,
                              hipStream_t stream) {
  const float* X  = (const float*)d_in[0];  // (N, 128)
  const float* W1 = (const float*)d_in[1];  // (256, 128)
  const float* b1 = (const float*)d_in[2];  // (128,)
  const float* W2 = (const float*)d_in[3];  // (128,)
  const float* b2 = (const float*)d_in[4];  // (1,)
  const float* U  = (const float*)d_in[5];  // (K, E)
  const int* src  = (const int*)d_in[6];    // (E,) sorted
  const int* dst  = (const int*)d_in[7];    // (E,)
  const int E = in_sizes[6];
  const int K = in_sizes[5] / E;
  const int N = in_sizes[0] / FEAT;

  // workspace: A (N*128 f32) | B (N*128 f32) | z (E f32) | rs (N+1 i32)
  float* A = (float*)d_ws;
  float* B = A + (size_t)N * HID;
  float* z = B + (size_t)N * HID;
  int* rs  = (int*)(z + E);

  float* out_sel  = (float*)d_out;                  // (K, N) as f32
  float* out_soft = (float*)d_out + (size_t)K * N;  // (K, E)

  hipLaunchKernelGGL(gemm_ab, dim3((N + 127) / 128, 4), dim3(256), 0, stream,
                     X, W1, A, B, N);
  hipLaunchKernelGGL(row_offsets, dim3((N + 256) / 256), dim3(256), 0, stream,
                     src, rs, N, E);
  hipLaunchKernelGGL(edge_z, dim3((E + 127) / 128), dim3(256), 0, stream,
                     A, B, b1, W2, b2, src, dst, z, E);
  hipLaunchKernelGGL(seg_sample, dim3((N + 7) / 8), dim3(256), 0, stream,
                     z, U, dst, rs, out_sel, out_soft, N, E, K);
}

// Round 5
// 246.005 us; speedup vs baseline: 1.1148x; 1.1148x over previous
//
#include <hip/hip_runtime.h>

#define FEAT 128
#define HID  128
#define XS_S 260  // 256 nodes + 4 pad; mult of 4 keeps b128 align; %32=4 -> 4-way write alias

// ---------------------------------------------------------------------------
// Kernel 1: [A|B] = X @ [W1[:128] | W1[128:]]  (N x 256 concat, fp32)
// Tile: 256 nodes x 64 concat-cols per block (grid 196 x 4). 4 waves/block;
// wave w owns 16 WAVE-UNIFORM cols -> W row reads go through readfirstlane to
// the SCALAR pipe (s_load_dwordx4, one address, SGPR-resident, feeds
// v_fma_f32 as the 1-SGPR operand). Lane owns 4 consecutive nodes -> x read
// is one ds_read_b128 from the transposed LDS X-chunk. Per wave-k:
// 1 ds_read_b128 + 4 s_load + 64 FMA => VALU-bound (LDS ~254 vs VALU 384
// cyc/CU-k at 12 waves/CU). R4 lesson: vector-global W reads pay 64-lane TA
// processing + unprefetchable L1 latency; LDS broadcast or SMEM only.
// ---------------------------------------------------------------------------
__global__ __launch_bounds__(256) void gemm_ab(
    const float* __restrict__ X, const float* __restrict__ W1,
    float* __restrict__ A, float* __restrict__ B, int N) {
  __shared__ float xs[32 * XS_S];
  const int t = threadIdx.x;
  const int lane = t & 63;
  const int n0 = blockIdx.x * 256;
  const int j0 = blockIdx.y * 64;  // concat col base: 0..127 -> A, 128..255 -> B
  // wave-uniform concat column for this wave, forced into SGPR
  const int jj = __builtin_amdgcn_readfirstlane(j0 + (t >> 6) * 16);
  const float* Wp = W1 + (jj < 128 ? jj : 128 * HID + (jj - 128));
  float* Obase = (jj < 128) ? (A + jj) : (B + (jj - 128));

  const int ln = t >> 3;       // staging node 0..31 (+rep*32)
  const int lf = (t & 7) * 4;  // staging k-local float4 base

  float acc[4][16];
#pragma unroll
  for (int r = 0; r < 4; ++r)
#pragma unroll
    for (int c = 0; c < 16; ++c) acc[r][c] = 0.f;

  for (int kc = 0; kc < 4; ++kc) {
    __syncthreads();
    // stage X chunk transposed: xs[k_local][node], 256 nodes
#pragma unroll
    for (int rep = 0; rep < 8; ++rep) {
      const int nl = ln + rep * 32;
      const int n = n0 + nl;
      float4 v = make_float4(0.f, 0.f, 0.f, 0.f);
      if (n < N) v = *(const float4*)(X + (size_t)n * FEAT + kc * 32 + lf);
      xs[(lf + 0) * XS_S + nl] = v.x;
      xs[(lf + 1) * XS_S + nl] = v.y;
      xs[(lf + 2) * XS_S + nl] = v.z;
      xs[(lf + 3) * XS_S + nl] = v.w;
    }
    __syncthreads();

#pragma unroll 4
    for (int k = 0; k < 32; ++k) {
      const float* wr = Wp + (size_t)(kc * 32 + k) * HID;  // uniform -> s_load
      const float4 w0 = *(const float4*)(wr);
      const float4 w1 = *(const float4*)(wr + 4);
      const float4 w2 = *(const float4*)(wr + 8);
      const float4 w3 = *(const float4*)(wr + 12);
      const float4 xv = *(const float4*)&xs[k * XS_S + lane * 4];
      const float xr[4] = {xv.x, xv.y, xv.z, xv.w};
      const float wv[16] = {w0.x, w0.y, w0.z, w0.w, w1.x, w1.y, w1.z, w1.w,
                            w2.x, w2.y, w2.z, w2.w, w3.x, w3.y, w3.z, w3.w};
#pragma unroll
      for (int r = 0; r < 4; ++r)
#pragma unroll
        for (int c = 0; c < 16; ++c)
          acc[r][c] = fmaf(xr[r], wv[c], acc[r][c]);
    }
  }

#pragma unroll
  for (int r = 0; r < 4; ++r) {
    const int n = n0 + lane * 4 + r;
    if (n < N) {
      float* o = Obase + (size_t)n * HID;
#pragma unroll
      for (int c4 = 0; c4 < 4; ++c4)
        *(float4*)(o + c4 * 4) = make_float4(acc[r][c4 * 4 + 0], acc[r][c4 * 4 + 1],
                                             acc[r][c4 * 4 + 2], acc[r][c4 * 4 + 3]);
    }
  }
}

// ---------------------------------------------------------------------------
// Kernel 2: CSR row offsets from sorted src via binary search. rs has N+1 ents.
// ---------------------------------------------------------------------------
__global__ __launch_bounds__(256) void row_offsets(
    const int* __restrict__ src, int* __restrict__ rs, int N, int E) {
  const int n = blockIdx.x * 256 + threadIdx.x;
  if (n > N) return;
  int lo = 0, hi = E;
  while (lo < hi) {
    const int mid = (lo + hi) >> 1;
    if (src[mid] < n) lo = mid + 1; else hi = mid;
  }
  rs[n] = lo;
}

// ---------------------------------------------------------------------------
// Kernel 3: z[e] = W2 . relu(A[src[e]] + B[dst[e]] + b1) + b2
// 16 lanes/edge, 2 edges per group, 4 batches per block with a 2-stage
// software pipeline: batch i+1's 8 row loads are issued BEFORE batch i's
// shfl-reduce chain, so misses stay in flight across the serial reduce.
// ---------------------------------------------------------------------------
struct Rows { float4 a0, a1, b0, b1, c0, c1, d0, d1; };

__device__ __forceinline__ void load_pair(
    const float* __restrict__ A, const float* __restrict__ B,
    const int* __restrict__ src, const int* __restrict__ dst,
    int e0, int E, int l, Rows& r) {
  const bool k0 = e0 < E, k1 = e0 + 1 < E;
  const int u0 = k0 ? src[e0] : 0;
  const int v0 = k0 ? dst[e0] : 0;
  const int u1 = k1 ? src[e0 + 1] : 0;
  const int v1 = k1 ? dst[e0 + 1] : 0;
  const float4* Au0 = (const float4*)(A + (size_t)u0 * HID) + l * 2;
  const float4* Bv0 = (const float4*)(B + (size_t)v0 * HID) + l * 2;
  const float4* Au1 = (const float4*)(A + (size_t)u1 * HID) + l * 2;
  const float4* Bv1 = (const float4*)(B + (size_t)v1 * HID) + l * 2;
  r.a0 = Au0[0]; r.a1 = Au0[1];
  r.b0 = Bv0[0]; r.b1 = Bv0[1];
  r.c0 = Au1[0]; r.c1 = Au1[1];
  r.d0 = Bv1[0]; r.d1 = Bv1[1];
}

__global__ __launch_bounds__(256) void edge_z(
    const float* __restrict__ A, const float* __restrict__ B,
    const float* __restrict__ b1, const float* __restrict__ W2,
    const float* __restrict__ b2, const int* __restrict__ src,
    const int* __restrict__ dst, float* __restrict__ z, int E) {
  const int g = threadIdx.x >> 4;
  const int l = threadIdx.x & 15;
  const int base = blockIdx.x * 128 + g * 2;

  const float4 c0 = *(const float4*)(b1 + l * 8);
  const float4 c1 = *(const float4*)(b1 + l * 8 + 4);
  const float4 w0 = *(const float4*)(W2 + l * 8);
  const float4 w1 = *(const float4*)(W2 + l * 8 + 4);
  const float bias2 = b2[0];

  Rows cur, nxt;
  load_pair(A, B, src, dst, base, E, l, cur);

#pragma unroll 4
  for (int it = 0; it < 4; ++it) {
    const int e0 = base + it * 32;
    if (it < 3) load_pair(A, B, src, dst, base + (it + 1) * 32, E, l, nxt);

    float p0 = fmaxf(cur.a0.x + cur.b0.x + c0.x, 0.f) * w0.x
             + fmaxf(cur.a0.y + cur.b0.y + c0.y, 0.f) * w0.y
             + fmaxf(cur.a0.z + cur.b0.z + c0.z, 0.f) * w0.z
             + fmaxf(cur.a0.w + cur.b0.w + c0.w, 0.f) * w0.w
             + fmaxf(cur.a1.x + cur.b1.x + c1.x, 0.f) * w1.x
             + fmaxf(cur.a1.y + cur.b1.y + c1.y, 0.f) * w1.y
             + fmaxf(cur.a1.z + cur.b1.z + c1.z, 0.f) * w1.z
             + fmaxf(cur.a1.w + cur.b1.w + c1.w, 0.f) * w1.w;
    float p1 = fmaxf(cur.c0.x + cur.d0.x + c0.x, 0.f) * w0.x
             + fmaxf(cur.c0.y + cur.d0.y + c0.y, 0.f) * w0.y
             + fmaxf(cur.c0.z + cur.d0.z + c0.z, 0.f) * w0.z
             + fmaxf(cur.c0.w + cur.d0.w + c0.w, 0.f) * w0.w
             + fmaxf(cur.c1.x + cur.d1.x + c1.x, 0.f) * w1.x
             + fmaxf(cur.c1.y + cur.d1.y + c1.y, 0.f) * w1.y
             + fmaxf(cur.c1.z + cur.d1.z + c1.z, 0.f) * w1.z
             + fmaxf(cur.c1.w + cur.d1.w + c1.w, 0.f) * w1.w;

#pragma unroll
    for (int m = 8; m >= 1; m >>= 1) {
      p0 += __shfl_xor(p0, m);
      p1 += __shfl_xor(p1, m);
    }
    if (l == 0 && e0 < E) {
      z[e0] = p0 + bias2;
      if (e0 + 1 < E) z[e0 + 1] = p1 + bias2;
    }
    cur = nxt;
  }
}

// ---------------------------------------------------------------------------
// Kernel 4: per-node log-softmax + K Gumbel rounds. TWO nodes per wave
// (half-wave each; deg<=32 fast path). ex = exp(s) space: argmax(ex) ==
// argmax(s); fused max+argmax pair reduction; fast __logf/__expf.
// ---------------------------------------------------------------------------
__global__ __launch_bounds__(256) void seg_sample(
    const float* __restrict__ z, const float* __restrict__ U,
    const int* __restrict__ dst, const int* __restrict__ rs,
    float* __restrict__ out_sel, float* __restrict__ out_soft,
    int N, int E, int K) {
  const int t = threadIdx.x;
  const int lane = t & 63;
  const int half = lane >> 5;
  const int hl = lane & 31;
  const int n = blockIdx.x * 8 + (t >> 6) * 2 + half;
  const float INVTAU = 1.0f / 0.9991f;

  int start = 0, deg = 0;
  if (n < N) { start = rs[n]; deg = rs[n + 1] - start; }

  if (__all(deg <= 32)) {
    // ---- fast path: half-wave per node ----
    if (n >= N) return;
    if (deg == 0) {
      if (hl == 0)
        for (int k = 0; k < K; ++k) out_sel[(size_t)k * N + n] = -2147483648.0f;
      return;
    }
    const bool act = hl < deg;
    const int e = start + (act ? hl : 0);
    const float zv = act ? z[e] : -INFINITY;
    const int d = act ? dst[e] : -1;

    float zmax = zv;
#pragma unroll
    for (int m = 16; m >= 1; m >>= 1) zmax = fmaxf(zmax, __shfl_xor(zmax, m));
    float den = act ? __expf(zv - zmax) : 0.f;
#pragma unroll
    for (int m = 16; m >= 1; m >>= 1) den += __shfl_xor(den, m);
    const float lpb = (zv - zmax) - __logf(den);  // per-edge log-prob

    for (int k = 0; k < K; ++k) {
      float ex = 0.f;
      if (act) {
        const float uu = U[(size_t)k * E + e];
        const float t2 = -__logf(uu);
        const float g = -__logf(t2);
        ex = __expf((lpb + g) * INVTAU);  // exp(s); s in [-19, 15] -> safe
      }
      float d2 = ex;
      float mx = ex;
      int md = d;
#pragma unroll
      for (int m = 16; m >= 1; m >>= 1) {
        d2 += __shfl_xor(d2, m);
        const float ox = __shfl_xor(mx, m);
        const int od = __shfl_xor(md, m);
        if (ox > mx) { mx = ox; md = od; }
        else if (ox == mx) md = max(md, od);
      }
      if (hl == 0) out_sel[(size_t)k * N + n] = (float)md;
      if (act) {
        const float inv = __builtin_amdgcn_rcpf(d2);
        out_soft[(size_t)k * E + e] = ex * inv;
      }
    }
    return;
  }

  // ---- general path (some deg > 32, rare): full wave per node, x2 ----
  const int wbase = blockIdx.x * 8 + (t >> 6) * 2;
  for (int j = 0; j < 2; ++j) {
    const int nn = wbase + j;
    if (nn >= N) continue;
    const int st = rs[nn];
    const int dg = rs[nn + 1] - st;
    if (dg == 0) {
      if (lane == 0)
        for (int k = 0; k < K; ++k) out_sel[(size_t)k * N + nn] = -2147483648.0f;
      continue;
    }
    float zmax = -INFINITY;
    for (int c = lane; c < dg; c += 64) zmax = fmaxf(zmax, z[st + c]);
#pragma unroll
    for (int m = 32; m >= 1; m >>= 1) zmax = fmaxf(zmax, __shfl_xor(zmax, m));
    float den = 0.f;
    for (int c = lane; c < dg; c += 64) den += expf(z[st + c] - zmax);
#pragma unroll
    for (int m = 32; m >= 1; m >>= 1) den += __shfl_xor(den, m);
    const float logd = logf(den);

    for (int k = 0; k < K; ++k) {
      float m2 = -INFINITY;
      for (int c = lane; c < dg; c += 64) {
        const int e = st + c;
        const float g = -logf(-logf(U[(size_t)k * E + e]));
        const float s = ((z[e] - zmax) - logd + g) * INVTAU;
        m2 = fmaxf(m2, s);
      }
#pragma unroll
      for (int m = 32; m >= 1; m >>= 1) m2 = fmaxf(m2, __shfl_xor(m2, m));
      float d2 = 0.f;
      int cand = -1;
      for (int c = lane; c < dg; c += 64) {
        const int e = st + c;
        const float g = -logf(-logf(U[(size_t)k * E + e]));
        const float s = ((z[e] - zmax) - logd + g) * INVTAU;
        d2 += expf(s - m2);
        if (s >= m2) cand = max(cand, dst[e]);
      }
#pragma unroll
      for (int m = 32; m >= 1; m >>= 1) d2 += __shfl_xor(d2, m);
#pragma unroll
      for (int m = 32; m >= 1; m >>= 1) cand = max(cand, __shfl_xor(cand, m));
      if (lane == 0) out_sel[(size_t)k * N + nn] = (float)cand;
      for (int c = lane; c < dg; c += 64) {
        const int e = st + c;
        const float g = -logf(-logf(U[(size_t)k * E + e]));
        const float s = ((z[e] - zmax) - logd + g) * INVTAU;
        out_soft[(size_t)k * E + e] = expf(s - m2) / d2;
      }
    }
  }
}

// ---------------------------------------------------------------------------
extern "C" void kernel_launch(void* const* d_in, const int* in_sizes, int n_in,
                              void* d_out, int out_size, void* d_ws, size_t ws_size,
                              hipStream_t stream) {
  const float* X  = (const float*)d_in[0];  // (N, 128)
  const float* W1 = (const float*)d_in[1];  // (256, 128)
  const float* b1 = (const float*)d_in[2];  // (128,)
  const float* W2 = (const float*)d_in[3];  // (128,)
  const float* b2 = (const float*)d_in[4];  // (1,)
  const float* U  = (const float*)d_in[5];  // (K, E)
  const int* src  = (const int*)d_in[6];    // (E,) sorted
  const int* dst  = (const int*)d_in[7];    // (E,)
  const int E = in_sizes[6];
  const int K = in_sizes[5] / E;
  const int N = in_sizes[0] / FEAT;

  // workspace: A (N*128 f32) | B (N*128 f32) | z (E f32) | rs (N+1 i32)
  float* A = (float*)d_ws;
  float* B = A + (size_t)N * HID;
  float* z = B + (size_t)N * HID;
  int* rs  = (int*)(z + E);

  float* out_sel  = (float*)d_out;                  // (K, N) as f32
  float* out_soft = (float*)d_out + (size_t)K * N;  // (K, E)

  hipLaunchKernelGGL(gemm_ab, dim3((N + 255) / 256, 4), dim3(256), 0, stream,
                     X, W1, A, B, N);
  hipLaunchKernelGGL(row_offsets, dim3((N + 256) / 256), dim3(256), 0, stream,
                     src, rs, N, E);
  hipLaunchKernelGGL(edge_z, dim3((E + 127) / 128), dim3(256), 0, stream,
                     A, B, b1, W2, b2, src, dst, z, E);
  hipLaunchKernelGGL(seg_sample, dim3((N + 7) / 8), dim3(256), 0, stream,
                     z, U, dst, rs, out_sel, out_soft, N, E, K);
}